// Round 5
// baseline (401.620 us; speedup 1.0000x reference)
//
#include <hip/hip_runtime.h>
#include <hip/hip_bf16.h>
#include <math.h>

#define IN_F 256
#define OUT_F 128
#define ALPHA 0.2f

#define BSH 7                  // 128 nodes per bucket
#define BNODES 128
#define NSLOT 8
#define CAP 5120               // max edges/bucket: mean 4096, sigma ~64 -> +16 sigma
#define MAXNB8 3200            // buckets*8 upper bound for LDS histogram

typedef __hip_bfloat162 bf2;

static __device__ __forceinline__ bf2 make_bf2(float x, float y) {
    bf2 r;
    r.x = __float2bfloat16(x);
    r.y = __float2bfloat16(y);
    return r;
}

// ---------------------------------------------------------------------------
// zero cnt2
__global__ void zero2_kernel(int* __restrict__ cnt2, int m) {
    int i = blockIdx.x * blockDim.x + threadIdx.x;
    if (i < m) cnt2[i] = 0;
}

// histogram over (bucket,slot). slot = (edge_idx>>8)&7 — matches scatter's blockIdx&7.
__global__ __launch_bounds__(256) void hist_kernel(const int* __restrict__ src,
                                                   int* __restrict__ cnt2, int e, int nb8) {
    __shared__ int lh[MAXNB8];
    for (int i = threadIdx.x; i < nb8; i += 256) lh[i] = 0;
    __syncthreads();
    int stride = gridDim.x * 256;
    for (int i = blockIdx.x * 256 + threadIdx.x; i < e; i += stride) {
        int s = src[i];
        int slot = (i >> 8) & 7;
        atomicAdd(&lh[((s >> BSH) << 3) + slot], 1);
    }
    __syncthreads();
    for (int i = threadIdx.x; i < nb8; i += 256) {
        int v = lh[i];
        if (v) atomicAdd(&cnt2[i], v);
    }
}

// single-block exclusive scan of cnt2 -> scan2[0..nb8], cursor copy; offs[n]=e.
__global__ __launch_bounds__(256) void scan2_kernel(const int* __restrict__ cnt2,
                                                    int* __restrict__ scan2,
                                                    int* __restrict__ cursor2,
                                                    int* __restrict__ offs,
                                                    int nb8, int n, int e) {
    __shared__ int ls[256];
    int tid = threadIdx.x;
    int ch = (nb8 + 255) / 256;
    int start = tid * ch;
    int end = start + ch; if (end > nb8) end = nb8;
    int sum = 0;
    for (int i = start; i < end; i++) sum += cnt2[i];
    ls[tid] = sum;
    __syncthreads();
    for (int off = 1; off < 256; off <<= 1) {
        int v = (tid >= off) ? ls[tid - off] : 0;
        __syncthreads();
        ls[tid] += v;
        __syncthreads();
    }
    int run = ls[tid] - sum;
    for (int i = start; i < end; i++) {
        scan2[i] = run; cursor2[i] = run;
        run += cnt2[i];
    }
    if (tid == 255) scan2[nb8] = ls[255];
    if (tid == 0) offs[n] = e;
}

// scatter packed (local_src<<17)|dst into (bucket,slot) segments. 4 B/edge.
__global__ __launch_bounds__(256) void scatter_kernel(const int* __restrict__ src,
                                                      const int* __restrict__ dst,
                                                      int* __restrict__ cursor2,
                                                      unsigned int* __restrict__ bin, int e) {
    int i = blockIdx.x * 256 + threadIdx.x;
    if (i >= e) return;
    int s = src[i], d = dst[i];
    int idx = ((s >> BSH) << 3) + ((i >> 8) & 7);
    int pos = atomicAdd(&cursor2[idx], 1);
    bin[pos] = ((unsigned int)(s & (BNODES - 1)) << 17) | (unsigned int)d;
}

// per-bucket LDS counting sort (in place) + write offs for the bucket's nodes.
__global__ __launch_bounds__(256) void sort_kernel(const int* __restrict__ scan2,
                                                   unsigned int* __restrict__ bin,
                                                   int* __restrict__ offs, int n) {
    __shared__ unsigned int ebuf[CAP];
    __shared__ int lh[BNODES];
    __shared__ int lx[BNODES];
    int b = blockIdx.x;
    int tid = threadIdx.x;
    int base = scan2[b << 3];
    int end  = scan2[(b + 1) << 3];
    int K = end - base;
    if (K > CAP) K = CAP;  // statistically impossible; guards LDS OOB
    for (int l = tid; l < BNODES; l += 256) lh[l] = 0;
    __syncthreads();
    for (int i = tid; i < K; i += 256) {
        unsigned int p = bin[base + i];
        ebuf[i] = p;
        atomicAdd(&lh[p >> 17], 1);
    }
    __syncthreads();
    int own = (tid < BNODES) ? lh[tid] : 0;
    for (int off = 1; off < BNODES; off <<= 1) {
        int v = (tid >= off && tid < BNODES) ? lh[tid - off] : 0;
        __syncthreads();
        if (tid < BNODES) lh[tid] += v;
        __syncthreads();
    }
    if (tid < BNODES) {
        int ex = lh[tid] - own;
        lx[tid] = ex;
        int node = (b << BSH) + tid;
        if (node < n) offs[node] = base + ex;
    }
    __syncthreads();
    for (int i = tid; i < K; i += 256) {
        unsigned int p = ebuf[i];
        int r = atomicAdd(&lx[p >> 17], 1);
        bin[base + r] = p;
    }
}

// ---------------------------------------------------------------------------
// GEMM Wh = h @ W.  128x128 tile, KB=32, 16x16 threads, 8x8 micro-tile.
// Epilogue writes bf16 Whb and fused f1 = Wh@a_src, f2 = Wh@a_dst.
#define TM 128
#define KB 32
__global__ __launch_bounds__(256) void gemm_kernel(const float* __restrict__ h,
                                                   const float* __restrict__ W,
                                                   const float* __restrict__ a_src,
                                                   const float* __restrict__ a_dst,
                                                   bf2* __restrict__ Whb,
                                                   float* __restrict__ f1,
                                                   float* __restrict__ f2, int n) {
    __shared__ float hs[KB * 128];
    __shared__ float ws[KB * 128];
    int tid = threadIdx.x;
    int tx = tid & 15, ty = tid >> 4;
    int r0 = blockIdx.x * TM;

    float acc[8][8];
#pragma unroll
    for (int i = 0; i < 8; i++)
#pragma unroll
        for (int j = 0; j < 8; j++) acc[i][j] = 0.f;

    for (int k0 = 0; k0 < IN_F; k0 += KB) {
        {
            int rt = tid >> 3;
            int kq = tid & 7;
#pragma unroll
            for (int p = 0; p < 4; p++) {
                int row_t = p * 32 + rt;
                int row = r0 + row_t;
                float4 v = make_float4(0.f, 0.f, 0.f, 0.f);
                if (row < n) v = *(const float4*)&h[(size_t)row * IN_F + k0 + kq * 4];
                const float* vf = (const float*)&v;
#pragma unroll
                for (int l = 0; l < 4; l++) {
                    int k = kq * 4 + l;
                    int swz = ((k >> 2) & 3) << 3;
                    hs[k * 128 + (row_t ^ swz)] = vf[l];
                }
            }
        }
        {
            int c4 = (tid & 31) * 4;
            int kk0 = tid >> 5;
#pragma unroll
            for (int p = 0; p < 4; p++) {
                int kk = p * 8 + kk0;
                *(float4*)&ws[kk * 128 + c4] = *(const float4*)&W[(size_t)(k0 + kk) * OUT_F + c4];
            }
        }
        __syncthreads();
#pragma unroll
        for (int k = 0; k < KB; k++) {
            int swz = ((k >> 2) & 3) << 3;
            float2 hv[4], wv[4];
#pragma unroll
            for (int i = 0; i < 4; i++) hv[i] = *(const float2*)&hs[k * 128 + ((ty * 2 + 32 * i) ^ swz)];
#pragma unroll
            for (int j = 0; j < 4; j++) wv[j] = *(const float2*)&ws[k * 128 + tx * 2 + 32 * j];
#pragma unroll
            for (int i = 0; i < 4; i++)
#pragma unroll
                for (int j = 0; j < 4; j++) {
                    acc[2 * i][2 * j]         += hv[i].x * wv[j].x;
                    acc[2 * i][2 * j + 1]     += hv[i].x * wv[j].y;
                    acc[2 * i + 1][2 * j]     += hv[i].y * wv[j].x;
                    acc[2 * i + 1][2 * j + 1] += hv[i].y * wv[j].y;
                }
        }
        __syncthreads();
    }

#pragma unroll
    for (int i = 0; i < 4; i++)
#pragma unroll
        for (int di = 0; di < 2; di++) {
            int row = r0 + ty * 2 + 32 * i + di;
            if (row < n) {
#pragma unroll
                for (int j = 0; j < 4; j++) {
                    Whb[(size_t)row * 64 + tx + 16 * j] =
                        make_bf2(acc[2 * i + di][2 * j], acc[2 * i + di][2 * j + 1]);
                }
            }
        }

    float p1[8], p2[8];
#pragma unroll
    for (int r = 0; r < 8; r++) { p1[r] = 0.f; p2[r] = 0.f; }
    float2 asv[4], adv[4];
#pragma unroll
    for (int j = 0; j < 4; j++) {
        asv[j] = *(const float2*)&a_src[tx * 2 + 32 * j];
        adv[j] = *(const float2*)&a_dst[tx * 2 + 32 * j];
    }
#pragma unroll
    for (int r = 0; r < 8; r++)
#pragma unroll
        for (int j = 0; j < 4; j++) {
            p1[r] += acc[r][2 * j] * asv[j].x + acc[r][2 * j + 1] * asv[j].y;
            p2[r] += acc[r][2 * j] * adv[j].x + acc[r][2 * j + 1] * adv[j].y;
        }
#pragma unroll
    for (int mks = 1; mks < 16; mks <<= 1)
#pragma unroll
        for (int r = 0; r < 8; r++) {
            p1[r] += __shfl_xor(p1[r], mks, 64);
            p2[r] += __shfl_xor(p2[r], mks, 64);
        }
    if (tx == 0) {
#pragma unroll
        for (int i = 0; i < 4; i++)
#pragma unroll
            for (int di = 0; di < 2; di++) {
                int row = r0 + ty * 2 + 32 * i + di;
                if (row < n) {
                    f1[row] = p1[2 * i + di];
                    f2[row] = p2[2 * i + di];
                }
            }
    }
}

// ---------------------------------------------------------------------------
// agg: 1 wave/node; lane owns 2 cols. Recomputes ev from f1/f2 (L2-resident).
__global__ __launch_bounds__(256) void agg_kernel(const bf2* __restrict__ Whb,
                                                  const int* __restrict__ offs,
                                                  const float* __restrict__ f1,
                                                  const float* __restrict__ f2,
                                                  const unsigned int* __restrict__ bin,
                                                  float* __restrict__ out, int n) {
    int lane = threadIdx.x & 63;
    int node = blockIdx.x * 4 + (threadIdx.x >> 6);
    if (node >= n) return;
    int j0 = offs[node], j1 = offs[node + 1];
    float f1n = f1[node];
    float2 acc = make_float2(0.f, 0.f);
    float den = 0.f;
    int j = j0;
    for (; j + 4 <= j1; j += 4) {
        unsigned int p0 = bin[j];
        unsigned int p1 = bin[j + 1];
        unsigned int p2 = bin[j + 2];
        unsigned int p3 = bin[j + 3];
        int d0 = p0 & 0x1FFFF, d1 = p1 & 0x1FFFF, d2 = p2 & 0x1FFFF, d3 = p3 & 0x1FFFF;
        bf2 w0 = Whb[(size_t)d0 * 64 + lane];
        bf2 w1 = Whb[(size_t)d1 * 64 + lane];
        bf2 w2 = Whb[(size_t)d2 * 64 + lane];
        bf2 w3 = Whb[(size_t)d3 * 64 + lane];
        float e0 = f1n + f2[d0];
        float e1 = f1n + f2[d1];
        float e2 = f1n + f2[d2];
        float e3 = f1n + f2[d3];
        e0 = e0 > 0.f ? e0 : ALPHA * e0;
        e1 = e1 > 0.f ? e1 : ALPHA * e1;
        e2 = e2 > 0.f ? e2 : ALPHA * e2;
        e3 = e3 > 0.f ? e3 : ALPHA * e3;
        float x0 = __expf(e0), x1 = __expf(e1), x2 = __expf(e2), x3 = __expf(e3);
        float2 g0 = __bfloat1622float2(w0);
        float2 g1 = __bfloat1622float2(w1);
        float2 g2 = __bfloat1622float2(w2);
        float2 g3 = __bfloat1622float2(w3);
        acc.x += x0 * g0.x + x1 * g1.x + x2 * g2.x + x3 * g3.x;
        acc.y += x0 * g0.y + x1 * g1.y + x2 * g2.y + x3 * g3.y;
        den += x0 + x1 + x2 + x3;
    }
    for (; j < j1; j++) {
        unsigned int p = bin[j];
        int d = p & 0x1FFFF;
        bf2 w = Whb[(size_t)d * 64 + lane];
        float e = f1n + f2[d];
        e = e > 0.f ? e : ALPHA * e;
        float x = __expf(e);
        float2 g = __bfloat1622float2(w);
        acc.x += x * g.x;
        acc.y += x * g.y;
        den += x;
    }
    float2 r = make_float2(0.f, 0.f);
    if (j1 > j0) { r.x = acc.x / den; r.y = acc.y / den; }
    r.x = r.x > 0.f ? r.x : expm1f(r.x);
    r.y = r.y > 0.f ? r.y : expm1f(r.y);
    *(float2*)&out[(size_t)node * OUT_F + lane * 2] = r;
}

// ---------------------------------------------------------------------------
extern "C" void kernel_launch(void* const* d_in, const int* in_sizes, int n_in,
                              void* d_out, int out_size, void* d_ws, size_t ws_size,
                              hipStream_t stream) {
    const float* h     = (const float*)d_in[0];
    const int*   src   = (const int*)d_in[1];
    const int*   dst   = (const int*)d_in[2];
    const float* W     = (const float*)d_in[3];
    const float* a_src = (const float*)d_in[4];
    const float* a_dst = (const float*)d_in[5];
    float* out = (float*)d_out;

    const int N = in_sizes[0] / IN_F;   // 50000
    const int E = in_sizes[1];          // 1600000
    const int NB = (N + BNODES - 1) >> BSH;  // 391
    const int NB8 = NB * NSLOT;              // 3128

    char* ws = (char*)d_ws;
    size_t off = 0;
    auto alloc = [&](size_t bytes) -> void* {
        void* p = ws + off;
        off += (bytes + 255) & ~(size_t)255;
        return p;
    };
    bf2*   Whb     = (bf2*)alloc((size_t)N * 64 * 4);
    float* f1      = (float*)alloc((size_t)N * 4);
    float* f2      = (float*)alloc((size_t)N * 4);
    int*   cnt2    = (int*)alloc((size_t)NB8 * 4);
    int*   scan2   = (int*)alloc((size_t)(NB8 + 1) * 4);
    int*   cursor2 = (int*)alloc((size_t)NB8 * 4);
    int*   offs    = (int*)alloc((size_t)(N + 1) * 4);
    unsigned int* bin = (unsigned int*)alloc((size_t)E * 4);
    (void)ws_size; (void)n_in; (void)out_size;

    zero2_kernel<<<(NB8 + 255) / 256, 256, 0, stream>>>(cnt2, NB8);
    hist_kernel<<<128, 256, 0, stream>>>(src, cnt2, E, NB8);
    scan2_kernel<<<1, 256, 0, stream>>>(cnt2, scan2, cursor2, offs, NB8, N, E);
    scatter_kernel<<<(E + 255) / 256, 256, 0, stream>>>(src, dst, cursor2, bin, E);
    sort_kernel<<<NB, 256, 0, stream>>>(scan2, bin, offs, N);
    gemm_kernel<<<(N + TM - 1) / TM, 256, 0, stream>>>(h, W, a_src, a_dst, Whb, f1, f2, N);
    agg_kernel<<<(N + 3) / 4, 256, 0, stream>>>(Whb, offs, f1, f2, bin, out, N);
}

// Round 6
// 263.318 us; speedup vs baseline: 1.5252x; 1.5252x over previous
//
#include <hip/hip_runtime.h>
#include <hip/hip_bf16.h>
#include <math.h>

#define IN_F 256
#define OUT_F 128
#define ALPHA 0.2f

#define BSH 7                  // 128 nodes per coarse bucket
#define BNODES 128
#define CHUNK 8192             // edges per binning block
#define NBK 512                // padded bucket-scan width (nb=391 <= 512)
#define CAP 5120               // max edges/bucket: mean 4096, sigma ~64

typedef __hip_bfloat162 bf2;

static __device__ __forceinline__ bf2 make_bf2(float x, float y) {
    bf2 r;
    r.x = __float2bfloat16(x);
    r.y = __float2bfloat16(y);
    return r;
}

// ---------------------------------------------------------------------------
// zero bucket counts
__global__ void zero_kernel(int* __restrict__ cnt, int m) {
    int i = blockIdx.x * blockDim.x + threadIdx.x;
    if (i < m) cnt[i] = 0;
}

// per-chunk LDS histogram -> global bucket counts (one atomic per bucket per block)
__global__ __launch_bounds__(512) void hist_kernel(const int* __restrict__ src,
                                                   int* __restrict__ cnt, int e, int nb) {
    __shared__ int lh[NBK];
    int tid = threadIdx.x;
    int base = blockIdx.x * CHUNK;
    int count = e - base; if (count > CHUNK) count = CHUNK;
    for (int i = tid; i < nb; i += 512) lh[i] = 0;
    __syncthreads();
    for (int i = tid; i < count; i += 512) atomicAdd(&lh[src[base + i] >> BSH], 1);
    __syncthreads();
    for (int i = tid; i < nb; i += 512) {
        int v = lh[i];
        if (v) atomicAdd(&cnt[i], v);
    }
}

// single-block exclusive scan of cnt[0..nb) -> scan2[0..nb], cursor copy; offs[n]=e.
__global__ __launch_bounds__(512) void scan_kernel(const int* __restrict__ cnt,
                                                   int* __restrict__ scan2,
                                                   int* __restrict__ cursor,
                                                   int* __restrict__ offs,
                                                   int nb, int n, int e) {
    __shared__ int ls[NBK];
    int tid = threadIdx.x;
    int v = (tid < nb) ? cnt[tid] : 0;
    ls[tid] = v;
    __syncthreads();
#pragma unroll
    for (int off = 1; off < NBK; off <<= 1) {
        int t = (tid >= off) ? ls[tid - off] : 0;
        __syncthreads();
        ls[tid] += t;
        __syncthreads();
    }
    if (tid < nb) {
        int ex = ls[tid] - v;
        scan2[tid] = ex;
        cursor[tid] = ex;
    }
    if (tid == NBK - 1) scan2[nb] = ls[NBK - 1];
    if (tid == 0) offs[n] = e;
}

// LDS-staged binning scatter: chunk -> LDS grouped by bucket -> contiguous bursts.
__global__ __launch_bounds__(512) void scatter_bin_kernel(const int* __restrict__ src,
                                                          const int* __restrict__ dst,
                                                          int* __restrict__ cursor,
                                                          unsigned int* __restrict__ bin,
                                                          int e, int nb) {
    __shared__ unsigned int ebuf[CHUNK];   // 32 KB
    __shared__ int lh[NBK];
    __shared__ int ls[NBK];
    __shared__ int ebase[NBK];
    __shared__ int lx[NBK];
    __shared__ int gbase[NBK];
    int tid = threadIdx.x;
    int base = blockIdx.x * CHUNK;
    int count = e - base; if (count > CHUNK) count = CHUNK;

    for (int i = tid; i < nb; i += 512) lh[i] = 0;
    __syncthreads();
    for (int i = tid; i < count; i += 512) atomicAdd(&lh[src[base + i] >> BSH], 1);
    __syncthreads();
    // scan lh (padded to NBK)
    int v = (tid < nb) ? lh[tid] : 0;
    ls[tid] = v;
    __syncthreads();
#pragma unroll
    for (int off = 1; off < NBK; off <<= 1) {
        int t = (tid >= off) ? ls[tid - off] : 0;
        __syncthreads();
        ls[tid] += t;
        __syncthreads();
    }
    if (tid < nb) {
        int ex = ls[tid] - v;
        ebase[tid] = ex;
        lx[tid] = ex;
    }
    __syncthreads();
    // place packed payloads grouped by bucket
    for (int i = tid; i < count; i += 512) {
        int s = src[base + i], d = dst[base + i];
        int b = s >> BSH;
        int p = atomicAdd(&lx[b], 1);
        ebuf[p] = ((unsigned int)(s & (BNODES - 1)) << 17) | (unsigned int)d;
    }
    __syncthreads();
    // reserve one contiguous global range per non-empty bucket
    if (tid < nb) {
        int c = lh[tid];
        gbase[tid] = c ? atomicAdd(&cursor[tid], c) : 0;
    }
    __syncthreads();
    // burst copy: wave w handles buckets w, w+8, ...
    int wave = tid >> 6, lane = tid & 63;
    for (int b = wave; b < nb; b += 8) {
        int c = lh[b], eb = ebase[b], gb = gbase[b];
        for (int l = lane; l < c; l += 64) bin[gb + l] = ebuf[eb + l];
    }
}

// per-bucket LDS counting sort (in place) + write offs for the bucket's nodes.
__global__ __launch_bounds__(256) void sort_kernel(const int* __restrict__ scan2,
                                                   unsigned int* __restrict__ bin,
                                                   int* __restrict__ offs, int n) {
    __shared__ unsigned int ebuf[CAP];
    __shared__ int lh[BNODES];
    __shared__ int lx[BNODES];
    int b = blockIdx.x;
    int tid = threadIdx.x;
    int base = scan2[b];
    int end  = scan2[b + 1];
    int K = end - base;
    if (K > CAP) K = CAP;  // statistically impossible; guards LDS OOB
    for (int l = tid; l < BNODES; l += 256) lh[l] = 0;
    __syncthreads();
    for (int i = tid; i < K; i += 256) {
        unsigned int p = bin[base + i];
        ebuf[i] = p;
        atomicAdd(&lh[p >> 17], 1);
    }
    __syncthreads();
    int own = (tid < BNODES) ? lh[tid] : 0;
    for (int off = 1; off < BNODES; off <<= 1) {
        int v = (tid >= off && tid < BNODES) ? lh[tid - off] : 0;
        __syncthreads();
        if (tid < BNODES) lh[tid] += v;
        __syncthreads();
    }
    if (tid < BNODES) {
        int ex = lh[tid] - own;
        lx[tid] = ex;
        int node = (b << BSH) + tid;
        if (node < n) offs[node] = base + ex;
    }
    __syncthreads();
    for (int i = tid; i < K; i += 256) {
        unsigned int p = ebuf[i];
        int r = atomicAdd(&lx[p >> 17], 1);
        bin[base + r] = p;
    }
}

// ---------------------------------------------------------------------------
// GEMM Wh = h @ W.  128x128 tile, KB=32, 16x16 threads, 8x8 micro-tile.
// Epilogue writes bf16 Whb and fused f1 = Wh@a_src, f2 = Wh@a_dst.
#define TM 128
#define KB 32
__global__ __launch_bounds__(256) void gemm_kernel(const float* __restrict__ h,
                                                   const float* __restrict__ W,
                                                   const float* __restrict__ a_src,
                                                   const float* __restrict__ a_dst,
                                                   bf2* __restrict__ Whb,
                                                   float* __restrict__ f1,
                                                   float* __restrict__ f2, int n) {
    __shared__ float hs[KB * 128];
    __shared__ float ws[KB * 128];
    int tid = threadIdx.x;
    int tx = tid & 15, ty = tid >> 4;
    int r0 = blockIdx.x * TM;

    float acc[8][8];
#pragma unroll
    for (int i = 0; i < 8; i++)
#pragma unroll
        for (int j = 0; j < 8; j++) acc[i][j] = 0.f;

    for (int k0 = 0; k0 < IN_F; k0 += KB) {
        {
            int rt = tid >> 3;
            int kq = tid & 7;
#pragma unroll
            for (int p = 0; p < 4; p++) {
                int row_t = p * 32 + rt;
                int row = r0 + row_t;
                float4 v = make_float4(0.f, 0.f, 0.f, 0.f);
                if (row < n) v = *(const float4*)&h[(size_t)row * IN_F + k0 + kq * 4];
                const float* vf = (const float*)&v;
#pragma unroll
                for (int l = 0; l < 4; l++) {
                    int k = kq * 4 + l;
                    int swz = ((k >> 2) & 3) << 3;
                    hs[k * 128 + (row_t ^ swz)] = vf[l];
                }
            }
        }
        {
            int c4 = (tid & 31) * 4;
            int kk0 = tid >> 5;
#pragma unroll
            for (int p = 0; p < 4; p++) {
                int kk = p * 8 + kk0;
                *(float4*)&ws[kk * 128 + c4] = *(const float4*)&W[(size_t)(k0 + kk) * OUT_F + c4];
            }
        }
        __syncthreads();
#pragma unroll
        for (int k = 0; k < KB; k++) {
            int swz = ((k >> 2) & 3) << 3;
            float2 hv[4], wv[4];
#pragma unroll
            for (int i = 0; i < 4; i++) hv[i] = *(const float2*)&hs[k * 128 + ((ty * 2 + 32 * i) ^ swz)];
#pragma unroll
            for (int j = 0; j < 4; j++) wv[j] = *(const float2*)&ws[k * 128 + tx * 2 + 32 * j];
#pragma unroll
            for (int i = 0; i < 4; i++)
#pragma unroll
                for (int j = 0; j < 4; j++) {
                    acc[2 * i][2 * j]         += hv[i].x * wv[j].x;
                    acc[2 * i][2 * j + 1]     += hv[i].x * wv[j].y;
                    acc[2 * i + 1][2 * j]     += hv[i].y * wv[j].x;
                    acc[2 * i + 1][2 * j + 1] += hv[i].y * wv[j].y;
                }
        }
        __syncthreads();
    }

#pragma unroll
    for (int i = 0; i < 4; i++)
#pragma unroll
        for (int di = 0; di < 2; di++) {
            int row = r0 + ty * 2 + 32 * i + di;
            if (row < n) {
#pragma unroll
                for (int j = 0; j < 4; j++) {
                    Whb[(size_t)row * 64 + tx + 16 * j] =
                        make_bf2(acc[2 * i + di][2 * j], acc[2 * i + di][2 * j + 1]);
                }
            }
        }

    float p1[8], p2[8];
#pragma unroll
    for (int r = 0; r < 8; r++) { p1[r] = 0.f; p2[r] = 0.f; }
    float2 asv[4], adv[4];
#pragma unroll
    for (int j = 0; j < 4; j++) {
        asv[j] = *(const float2*)&a_src[tx * 2 + 32 * j];
        adv[j] = *(const float2*)&a_dst[tx * 2 + 32 * j];
    }
#pragma unroll
    for (int r = 0; r < 8; r++)
#pragma unroll
        for (int j = 0; j < 4; j++) {
            p1[r] += acc[r][2 * j] * asv[j].x + acc[r][2 * j + 1] * asv[j].y;
            p2[r] += acc[r][2 * j] * adv[j].x + acc[r][2 * j + 1] * adv[j].y;
        }
#pragma unroll
    for (int mks = 1; mks < 16; mks <<= 1)
#pragma unroll
        for (int r = 0; r < 8; r++) {
            p1[r] += __shfl_xor(p1[r], mks, 64);
            p2[r] += __shfl_xor(p2[r], mks, 64);
        }
    if (tx == 0) {
#pragma unroll
        for (int i = 0; i < 4; i++)
#pragma unroll
            for (int di = 0; di < 2; di++) {
                int row = r0 + ty * 2 + 32 * i + di;
                if (row < n) {
                    f1[row] = p1[2 * i + di];
                    f2[row] = p2[2 * i + di];
                }
            }
    }
}

// ---------------------------------------------------------------------------
// agg: 1 wave/node; lane owns 2 cols. Recomputes ev from f1/f2 (L2-resident).
__global__ __launch_bounds__(256) void agg_kernel(const bf2* __restrict__ Whb,
                                                  const int* __restrict__ offs,
                                                  const float* __restrict__ f1,
                                                  const float* __restrict__ f2,
                                                  const unsigned int* __restrict__ bin,
                                                  float* __restrict__ out, int n) {
    int lane = threadIdx.x & 63;
    int node = blockIdx.x * 4 + (threadIdx.x >> 6);
    if (node >= n) return;
    int j0 = offs[node], j1 = offs[node + 1];
    float f1n = f1[node];
    float2 acc = make_float2(0.f, 0.f);
    float den = 0.f;
    int j = j0;
    for (; j + 4 <= j1; j += 4) {
        unsigned int p0 = bin[j];
        unsigned int p1 = bin[j + 1];
        unsigned int p2 = bin[j + 2];
        unsigned int p3 = bin[j + 3];
        int d0 = p0 & 0x1FFFF, d1 = p1 & 0x1FFFF, d2 = p2 & 0x1FFFF, d3 = p3 & 0x1FFFF;
        bf2 w0 = Whb[(size_t)d0 * 64 + lane];
        bf2 w1 = Whb[(size_t)d1 * 64 + lane];
        bf2 w2 = Whb[(size_t)d2 * 64 + lane];
        bf2 w3 = Whb[(size_t)d3 * 64 + lane];
        float e0 = f1n + f2[d0];
        float e1 = f1n + f2[d1];
        float e2 = f1n + f2[d2];
        float e3 = f1n + f2[d3];
        e0 = e0 > 0.f ? e0 : ALPHA * e0;
        e1 = e1 > 0.f ? e1 : ALPHA * e1;
        e2 = e2 > 0.f ? e2 : ALPHA * e2;
        e3 = e3 > 0.f ? e3 : ALPHA * e3;
        float x0 = __expf(e0), x1 = __expf(e1), x2 = __expf(e2), x3 = __expf(e3);
        float2 g0 = __bfloat1622float2(w0);
        float2 g1 = __bfloat1622float2(w1);
        float2 g2 = __bfloat1622float2(w2);
        float2 g3 = __bfloat1622float2(w3);
        acc.x += x0 * g0.x + x1 * g1.x + x2 * g2.x + x3 * g3.x;
        acc.y += x0 * g0.y + x1 * g1.y + x2 * g2.y + x3 * g3.y;
        den += x0 + x1 + x2 + x3;
    }
    for (; j < j1; j++) {
        unsigned int p = bin[j];
        int d = p & 0x1FFFF;
        bf2 w = Whb[(size_t)d * 64 + lane];
        float e = f1n + f2[d];
        e = e > 0.f ? e : ALPHA * e;
        float x = __expf(e);
        float2 g = __bfloat1622float2(w);
        acc.x += x * g.x;
        acc.y += x * g.y;
        den += x;
    }
    float2 r = make_float2(0.f, 0.f);
    if (j1 > j0) { r.x = acc.x / den; r.y = acc.y / den; }
    r.x = r.x > 0.f ? r.x : expm1f(r.x);
    r.y = r.y > 0.f ? r.y : expm1f(r.y);
    *(float2*)&out[(size_t)node * OUT_F + lane * 2] = r;
}

// ---------------------------------------------------------------------------
extern "C" void kernel_launch(void* const* d_in, const int* in_sizes, int n_in,
                              void* d_out, int out_size, void* d_ws, size_t ws_size,
                              hipStream_t stream) {
    const float* h     = (const float*)d_in[0];
    const int*   src   = (const int*)d_in[1];
    const int*   dst   = (const int*)d_in[2];
    const float* W     = (const float*)d_in[3];
    const float* a_src = (const float*)d_in[4];
    const float* a_dst = (const float*)d_in[5];
    float* out = (float*)d_out;

    const int N = in_sizes[0] / IN_F;        // 50000
    const int E = in_sizes[1];               // 1600000
    const int NB = (N + BNODES - 1) >> BSH;  // 391 (must be <= NBK)
    const int NCH = (E + CHUNK - 1) / CHUNK; // 196

    char* ws = (char*)d_ws;
    size_t off = 0;
    auto alloc = [&](size_t bytes) -> void* {
        void* p = ws + off;
        off += (bytes + 255) & ~(size_t)255;
        return p;
    };
    bf2*   Whb    = (bf2*)alloc((size_t)N * 64 * 4);
    float* f1     = (float*)alloc((size_t)N * 4);
    float* f2     = (float*)alloc((size_t)N * 4);
    int*   cnt    = (int*)alloc((size_t)NB * 4);
    int*   scan2  = (int*)alloc((size_t)(NB + 1) * 4);
    int*   cursor = (int*)alloc((size_t)NB * 4);
    int*   offs   = (int*)alloc((size_t)(N + 1) * 4);
    unsigned int* bin = (unsigned int*)alloc((size_t)E * 4);
    (void)ws_size; (void)n_in; (void)out_size;

    zero_kernel<<<(NB + 255) / 256, 256, 0, stream>>>(cnt, NB);
    hist_kernel<<<NCH, 512, 0, stream>>>(src, cnt, E, NB);
    scan_kernel<<<1, 512, 0, stream>>>(cnt, scan2, cursor, offs, NB, N, E);
    scatter_bin_kernel<<<NCH, 512, 0, stream>>>(src, dst, cursor, bin, E, NB);
    sort_kernel<<<NB, 256, 0, stream>>>(scan2, bin, offs, N);
    gemm_kernel<<<(N + TM - 1) / TM, 256, 0, stream>>>(h, W, a_src, a_dst, Whb, f1, f2, N);
    agg_kernel<<<(N + 3) / 4, 256, 0, stream>>>(Whb, offs, f1, f2, bin, out, N);
}

// Round 7
// 249.517 us; speedup vs baseline: 1.6096x; 1.0553x over previous
//
#include <hip/hip_runtime.h>
#include <hip/hip_bf16.h>
#include <math.h>

#define IN_F 256
#define OUT_F 128
#define ALPHA 0.2f

#define BSH 7                  // 128 nodes per coarse bucket
#define BNODES 128
#define CHUNK 8192             // edges per binning block
#define NBK 512                // padded bucket-scan width (nb=391 <= 512)
#define CAP 5120               // max edges/bucket: mean 4096, sigma ~64

typedef __hip_bfloat162 bf2;
typedef __attribute__((ext_vector_type(8))) short short8;
typedef __attribute__((ext_vector_type(4))) float f32x4;

static __device__ __forceinline__ unsigned short f2bf(float x) {
    union { __hip_bfloat16 h; unsigned short u; } cv;
    cv.h = __float2bfloat16(x);
    return cv.u;
}

// ---------------------------------------------------------------------------
// zero bucket counts
__global__ void zero_kernel(int* __restrict__ cnt, int m) {
    int i = blockIdx.x * blockDim.x + threadIdx.x;
    if (i < m) cnt[i] = 0;
}

// per-chunk LDS histogram -> global bucket counts
__global__ __launch_bounds__(512) void hist_kernel(const int* __restrict__ src,
                                                   int* __restrict__ cnt, int e, int nb) {
    __shared__ int lh[NBK];
    int tid = threadIdx.x;
    int base = blockIdx.x * CHUNK;
    int count = e - base; if (count > CHUNK) count = CHUNK;
    for (int i = tid; i < nb; i += 512) lh[i] = 0;
    __syncthreads();
    for (int i = tid; i < count; i += 512) atomicAdd(&lh[src[base + i] >> BSH], 1);
    __syncthreads();
    for (int i = tid; i < nb; i += 512) {
        int v = lh[i];
        if (v) atomicAdd(&cnt[i], v);
    }
}

// single-block exclusive scan of cnt[0..nb) -> scan2[0..nb], cursor copy; offs[n]=e.
__global__ __launch_bounds__(512) void scan_kernel(const int* __restrict__ cnt,
                                                   int* __restrict__ scan2,
                                                   int* __restrict__ cursor,
                                                   int* __restrict__ offs,
                                                   int nb, int n, int e) {
    __shared__ int ls[NBK];
    int tid = threadIdx.x;
    int v = (tid < nb) ? cnt[tid] : 0;
    ls[tid] = v;
    __syncthreads();
#pragma unroll
    for (int off = 1; off < NBK; off <<= 1) {
        int t = (tid >= off) ? ls[tid - off] : 0;
        __syncthreads();
        ls[tid] += t;
        __syncthreads();
    }
    if (tid < nb) {
        int ex = ls[tid] - v;
        scan2[tid] = ex;
        cursor[tid] = ex;
    }
    if (tid == NBK - 1) scan2[nb] = ls[NBK - 1];
    if (tid == 0) offs[n] = e;
}

// LDS-staged binning scatter: chunk -> LDS grouped by bucket -> contiguous bursts.
__global__ __launch_bounds__(512) void scatter_bin_kernel(const int* __restrict__ src,
                                                          const int* __restrict__ dst,
                                                          int* __restrict__ cursor,
                                                          unsigned int* __restrict__ bin,
                                                          int e, int nb) {
    __shared__ unsigned int ebuf[CHUNK];   // 32 KB
    __shared__ int lh[NBK];
    __shared__ int ls[NBK];
    __shared__ int ebase[NBK];
    __shared__ int lx[NBK];
    __shared__ int gbase[NBK];
    int tid = threadIdx.x;
    int base = blockIdx.x * CHUNK;
    int count = e - base; if (count > CHUNK) count = CHUNK;

    for (int i = tid; i < nb; i += 512) lh[i] = 0;
    __syncthreads();
    for (int i = tid; i < count; i += 512) atomicAdd(&lh[src[base + i] >> BSH], 1);
    __syncthreads();
    int v = (tid < nb) ? lh[tid] : 0;
    ls[tid] = v;
    __syncthreads();
#pragma unroll
    for (int off = 1; off < NBK; off <<= 1) {
        int t = (tid >= off) ? ls[tid - off] : 0;
        __syncthreads();
        ls[tid] += t;
        __syncthreads();
    }
    if (tid < nb) {
        int ex = ls[tid] - v;
        ebase[tid] = ex;
        lx[tid] = ex;
    }
    __syncthreads();
    for (int i = tid; i < count; i += 512) {
        int s = src[base + i], d = dst[base + i];
        int b = s >> BSH;
        int p = atomicAdd(&lx[b], 1);
        ebuf[p] = ((unsigned int)(s & (BNODES - 1)) << 17) | (unsigned int)d;
    }
    __syncthreads();
    if (tid < nb) {
        int c = lh[tid];
        gbase[tid] = c ? atomicAdd(&cursor[tid], c) : 0;
    }
    __syncthreads();
    int wave = tid >> 6, lane = tid & 63;
    for (int b = wave; b < nb; b += 8) {
        int c = lh[b], eb = ebase[b], gb = gbase[b];
        for (int l = lane; l < c; l += 64) bin[gb + l] = ebuf[eb + l];
    }
}

// per-bucket LDS counting sort (in place) + write offs for the bucket's nodes.
__global__ __launch_bounds__(256) void sort_kernel(const int* __restrict__ scan2,
                                                   unsigned int* __restrict__ bin,
                                                   int* __restrict__ offs, int n) {
    __shared__ unsigned int ebuf[CAP];
    __shared__ int lh[BNODES];
    __shared__ int lx[BNODES];
    int b = blockIdx.x;
    int tid = threadIdx.x;
    int base = scan2[b];
    int end  = scan2[b + 1];
    int K = end - base;
    if (K > CAP) K = CAP;
    for (int l = tid; l < BNODES; l += 256) lh[l] = 0;
    __syncthreads();
    for (int i = tid; i < K; i += 256) {
        unsigned int p = bin[base + i];
        ebuf[i] = p;
        atomicAdd(&lh[p >> 17], 1);
    }
    __syncthreads();
    int own = (tid < BNODES) ? lh[tid] : 0;
    for (int off = 1; off < BNODES; off <<= 1) {
        int v = (tid >= off && tid < BNODES) ? lh[tid - off] : 0;
        __syncthreads();
        if (tid < BNODES) lh[tid] += v;
        __syncthreads();
    }
    if (tid < BNODES) {
        int ex = lh[tid] - own;
        lx[tid] = ex;
        int node = (b << BSH) + tid;
        if (node < n) offs[node] = base + ex;
    }
    __syncthreads();
    for (int i = tid; i < K; i += 256) {
        unsigned int p = ebuf[i];
        int r = atomicAdd(&lx[p >> 17], 1);
        bin[base + r] = p;
    }
}

// ---------------------------------------------------------------------------
// MFMA bf16 GEMM: Wh = h @ W (K=256, N=128), 64-row tiles, 782 blocks.
// Per k-step: stage A(64x32) + B^T(128x32) in LDS (stride 40 = 2-way-free banks).
// Wave w owns rows w*16..w*16+15, all 128 cols (8 MFMAs/k-step).
// Epilogue: bf16 Whb store + fused f1/f2 (quad-local xor reduction).
__global__ __launch_bounds__(256) void gemm_kernel(const float* __restrict__ h,
                                                   const float* __restrict__ W,
                                                   const float* __restrict__ a_src,
                                                   const float* __restrict__ a_dst,
                                                   unsigned short* __restrict__ Whb,
                                                   float* __restrict__ f1,
                                                   float* __restrict__ f2, int n) {
    __shared__ unsigned short as_[64 * 40];
    __shared__ unsigned short bs_[128 * 40];
    int tid = threadIdx.x;
    int wv = tid >> 6, lane = tid & 63;
    int m = lane & 15, quad = lane >> 4;
    int r0 = blockIdx.x * 64;

    f32x4 acc[8];
#pragma unroll
    for (int c = 0; c < 8; c++) acc[c] = (f32x4){0.f, 0.f, 0.f, 0.f};

    for (int k0 = 0; k0 < IN_F; k0 += 32) {
        // stage A: 64 rows x 32 k
        {
            int arow = tid >> 3;     // 0..31
            int kq = tid & 7;        // 0..7
#pragma unroll
            for (int p = 0; p < 2; p++) {
                int row = arow + p * 32;
                int grow = r0 + row;
                float4 v = make_float4(0.f, 0.f, 0.f, 0.f);
                if (grow < n) v = *(const float4*)&h[(size_t)grow * IN_F + k0 + kq * 4];
                ushort4 b;
                b.x = f2bf(v.x); b.y = f2bf(v.y); b.z = f2bf(v.z); b.w = f2bf(v.w);
                *(ushort4*)&as_[row * 40 + kq * 4] = b;
            }
        }
        // stage B transposed: bs[n][k], 32 k x 128 n
        {
            int c4 = (tid & 31) * 4;
            int kb = tid >> 5;       // 0..7
#pragma unroll
            for (int p = 0; p < 4; p++) {
                int kk = p * 8 + kb;
                float4 wv4 = *(const float4*)&W[(size_t)(k0 + kk) * OUT_F + c4];
                bs_[(c4 + 0) * 40 + kk] = f2bf(wv4.x);
                bs_[(c4 + 1) * 40 + kk] = f2bf(wv4.y);
                bs_[(c4 + 2) * 40 + kk] = f2bf(wv4.z);
                bs_[(c4 + 3) * 40 + kk] = f2bf(wv4.w);
            }
        }
        __syncthreads();
        short8 af = *(const short8*)&as_[(wv * 16 + m) * 40 + quad * 8];
#pragma unroll
        for (int c = 0; c < 8; c++) {
            short8 bfv = *(const short8*)&bs_[(c * 16 + m) * 40 + quad * 8];
            acc[c] = __builtin_amdgcn_mfma_f32_16x16x32_bf16(af, bfv, acc[c], 0, 0, 0);
        }
        __syncthreads();
    }

    // epilogue: Whb bf16 store. D layout: col = c*16+m, row = base_row+reg.
    int base_row = r0 + wv * 16 + quad * 4;
#pragma unroll
    for (int reg = 0; reg < 4; reg++) {
        int rg = base_row + reg;
        if (rg < n) {
#pragma unroll
            for (int c = 0; c < 8; c++)
                Whb[(size_t)rg * OUT_F + c * 16 + m] = f2bf(acc[c][reg]);
        }
    }

    // fused f1/f2
    float a1[8], a2[8];
#pragma unroll
    for (int c = 0; c < 8; c++) {
        a1[c] = a_src[c * 16 + m];
        a2[c] = a_dst[c * 16 + m];
    }
    float p1[4] = {0.f, 0.f, 0.f, 0.f}, p2[4] = {0.f, 0.f, 0.f, 0.f};
#pragma unroll
    for (int c = 0; c < 8; c++)
#pragma unroll
        for (int reg = 0; reg < 4; reg++) {
            p1[reg] += acc[c][reg] * a1[c];
            p2[reg] += acc[c][reg] * a2[c];
        }
#pragma unroll
    for (int mask = 1; mask < 16; mask <<= 1)
#pragma unroll
        for (int reg = 0; reg < 4; reg++) {
            p1[reg] += __shfl_xor(p1[reg], mask, 64);
            p2[reg] += __shfl_xor(p2[reg], mask, 64);
        }
    if (m == 0) {
#pragma unroll
        for (int reg = 0; reg < 4; reg++) {
            int rg = base_row + reg;
            if (rg < n) { f1[rg] = p1[reg]; f2[rg] = p2[reg]; }
        }
    }
}

// ---------------------------------------------------------------------------
// agg: 1 wave/node; lane owns 2 cols. Recomputes ev from f1/f2 (L2-resident).
__global__ __launch_bounds__(256) void agg_kernel(const bf2* __restrict__ Whb,
                                                  const int* __restrict__ offs,
                                                  const float* __restrict__ f1,
                                                  const float* __restrict__ f2,
                                                  const unsigned int* __restrict__ bin,
                                                  float* __restrict__ out, int n) {
    int lane = threadIdx.x & 63;
    int node = blockIdx.x * 4 + (threadIdx.x >> 6);
    if (node >= n) return;
    int j0 = offs[node], j1 = offs[node + 1];
    float f1n = f1[node];
    float2 acc = make_float2(0.f, 0.f);
    float den = 0.f;
    int j = j0;
    for (; j + 4 <= j1; j += 4) {
        unsigned int p0 = bin[j];
        unsigned int p1 = bin[j + 1];
        unsigned int p2 = bin[j + 2];
        unsigned int p3 = bin[j + 3];
        int d0 = p0 & 0x1FFFF, d1 = p1 & 0x1FFFF, d2 = p2 & 0x1FFFF, d3 = p3 & 0x1FFFF;
        bf2 w0 = Whb[(size_t)d0 * 64 + lane];
        bf2 w1 = Whb[(size_t)d1 * 64 + lane];
        bf2 w2 = Whb[(size_t)d2 * 64 + lane];
        bf2 w3 = Whb[(size_t)d3 * 64 + lane];
        float e0 = f1n + f2[d0];
        float e1 = f1n + f2[d1];
        float e2 = f1n + f2[d2];
        float e3 = f1n + f2[d3];
        e0 = e0 > 0.f ? e0 : ALPHA * e0;
        e1 = e1 > 0.f ? e1 : ALPHA * e1;
        e2 = e2 > 0.f ? e2 : ALPHA * e2;
        e3 = e3 > 0.f ? e3 : ALPHA * e3;
        float x0 = __expf(e0), x1 = __expf(e1), x2 = __expf(e2), x3 = __expf(e3);
        float2 g0 = __bfloat1622float2(w0);
        float2 g1 = __bfloat1622float2(w1);
        float2 g2 = __bfloat1622float2(w2);
        float2 g3 = __bfloat1622float2(w3);
        acc.x += x0 * g0.x + x1 * g1.x + x2 * g2.x + x3 * g3.x;
        acc.y += x0 * g0.y + x1 * g1.y + x2 * g2.y + x3 * g3.y;
        den += x0 + x1 + x2 + x3;
    }
    for (; j < j1; j++) {
        unsigned int p = bin[j];
        int d = p & 0x1FFFF;
        bf2 w = Whb[(size_t)d * 64 + lane];
        float e = f1n + f2[d];
        e = e > 0.f ? e : ALPHA * e;
        float x = __expf(e);
        float2 g = __bfloat1622float2(w);
        acc.x += x * g.x;
        acc.y += x * g.y;
        den += x;
    }
    float2 r = make_float2(0.f, 0.f);
    if (j1 > j0) { r.x = acc.x / den; r.y = acc.y / den; }
    r.x = r.x > 0.f ? r.x : expm1f(r.x);
    r.y = r.y > 0.f ? r.y : expm1f(r.y);
    *(float2*)&out[(size_t)node * OUT_F + lane * 2] = r;
}

// ---------------------------------------------------------------------------
extern "C" void kernel_launch(void* const* d_in, const int* in_sizes, int n_in,
                              void* d_out, int out_size, void* d_ws, size_t ws_size,
                              hipStream_t stream) {
    const float* h     = (const float*)d_in[0];
    const int*   src   = (const int*)d_in[1];
    const int*   dst   = (const int*)d_in[2];
    const float* W     = (const float*)d_in[3];
    const float* a_src = (const float*)d_in[4];
    const float* a_dst = (const float*)d_in[5];
    float* out = (float*)d_out;

    const int N = in_sizes[0] / IN_F;        // 50000
    const int E = in_sizes[1];               // 1600000
    const int NB = (N + BNODES - 1) >> BSH;  // 391 (must be <= NBK)
    const int NCH = (E + CHUNK - 1) / CHUNK; // 196

    char* ws = (char*)d_ws;
    size_t off = 0;
    auto alloc = [&](size_t bytes) -> void* {
        void* p = ws + off;
        off += (bytes + 255) & ~(size_t)255;
        return p;
    };
    unsigned short* Whb = (unsigned short*)alloc((size_t)N * OUT_F * 2);
    float* f1     = (float*)alloc((size_t)N * 4);
    float* f2     = (float*)alloc((size_t)N * 4);
    int*   cnt    = (int*)alloc((size_t)NB * 4);
    int*   scan2  = (int*)alloc((size_t)(NB + 1) * 4);
    int*   cursor = (int*)alloc((size_t)NB * 4);
    int*   offs   = (int*)alloc((size_t)(N + 1) * 4);
    unsigned int* bin = (unsigned int*)alloc((size_t)E * 4);
    (void)ws_size; (void)n_in; (void)out_size;

    zero_kernel<<<(NB + 255) / 256, 256, 0, stream>>>(cnt, NB);
    hist_kernel<<<NCH, 512, 0, stream>>>(src, cnt, E, NB);
    scan_kernel<<<1, 512, 0, stream>>>(cnt, scan2, cursor, offs, NB, N, E);
    scatter_bin_kernel<<<NCH, 512, 0, stream>>>(src, dst, cursor, bin, E, NB);
    sort_kernel<<<NB, 256, 0, stream>>>(scan2, bin, offs, N);
    gemm_kernel<<<(N + 63) / 64, 256, 0, stream>>>(h, W, a_src, a_dst, Whb, f1, f2, N);
    agg_kernel<<<(N + 3) / 4, 256, 0, stream>>>((const bf2*)Whb, offs, f1, f2, bin, out, N);
}